// Round 5
// baseline (569.222 us; speedup 1.0000x reference)
//
#include <hip/hip_runtime.h>

#define DIM 128
#define K_CL 512
#define BM 128          // points per block tile
#define CC 128          // centers per chunk (4 chunks)
#define TAU1 0.75f      // hi-only margin -> tier-2 (bf16 hi/lo re-rank)
#define TAU2 0.02f      // hi/lo-split margin -> tier-3 (fp64 rescue)
#define LISTA_CAP 65536
#define LISTB_CAP 16384
#define SS_PARTS 128    // point partitions for segment-sum
#define QCAP 2048

typedef unsigned int uint;
typedef unsigned short ushort;
using short8 = __attribute__((ext_vector_type(8))) short;
using f32x4  = __attribute__((ext_vector_type(4))) float;
using us8    = __attribute__((ext_vector_type(8))) unsigned short;

__device__ __forceinline__ ushort f2bf(float x) {
    uint u = __float_as_uint(x);
    u += 0x7fff + ((u >> 16) & 1);          // RNE
    return (ushort)(u >> 16);
}
__device__ __forceinline__ float bf2f(ushort h) {
    return __uint_as_float(((uint)h) << 16);
}

__device__ __forceinline__ void gload_lds16(const void* gsrc, void* ldst) {
    __builtin_amdgcn_global_load_lds(
        (const __attribute__((address_space(1))) unsigned int*)gsrc,
        (__attribute__((address_space(3))) unsigned int*)ldst,
        16, 0, 0);
}

// ---------------- kernel A: c2 (fp32) and c2d (fp64) ----------------
__global__ void c2_kernel(const float* __restrict__ C, float* __restrict__ c2,
                          double* __restrict__ c2d) {
    int k = blockIdx.x * 256 + threadIdx.x;
    if (k < K_CL) {
        const float* row = C + (size_t)k * DIM;
        float s = 0.f;
        double sd = 0.0;
        for (int d = 0; d < DIM; ++d) {
            s = fmaf(row[d], row[d], s);
            double v = (double)row[d];
            sd += v * v;
        }
        c2[k] = s;
        c2d[k] = sd;
    }
}

// ---------------- kernel A2: split C into bf16 hi|lo ----------------
// Cp[k][0:128] = hi, Cp[k][128:256] = lo
__global__ void convC_kernel(const float* __restrict__ C, ushort* __restrict__ Cp) {
    int e = blockIdx.x * 256 + threadIdx.x;   // 0..65535
    if (e < K_CL * DIM) {
        int p = e >> 7, d = e & 127;
        float x = C[e];
        ushort h = f2bf(x);
        float lo = x - bf2f(h);
        Cp[(size_t)p * 256 + d] = h;
        Cp[(size_t)p * 256 + 128 + d] = f2bf(lo);
    }
}

// ---------------- TIER 1: hi-only MFMA GEMM + argmin (all points) ----------------
// Fs: 128 rows x 16 granules (8 bf16 = 16B), granule g of row r at
//     pos = (g&8) | ((g^r)&7). Cs: whole 128-center chunk, same layout.
// 4 barrier-pairs/block, 256 MFMA/wave, 128 ds_read_b128/wave.
__global__ __launch_bounds__(256, 2)
void assign_hi(const float* __restrict__ F, const ushort* __restrict__ Cp,
               const float* __restrict__ c2g, float* __restrict__ assign_out,
               int* __restrict__ cntA, int* __restrict__ listA,
               int* __restrict__ cntB, int* __restrict__ listB, int N) {
    __shared__ __align__(16) ushort Fs[BM * 128];    // 32768 B
    __shared__ __align__(16) ushort Cs[128 * 128];   // 32768 B

    const int tid  = threadIdx.x;
    const int lane = tid & 63;
    const int wave = tid >> 6;
    const int quad = lane >> 4;
    const int l15  = lane & 15;
    const int wy   = wave >> 1;     // point half
    const int wx   = wave & 1;      // center half
    const int p0   = blockIdx.x * BM;

    // ---- stage Fs: fp32 -> bf16 hi, swizzled ----
#pragma unroll
    for (int t = 0; t < 8; ++t) {
        int G = tid + 256 * t;          // 0..2047 granules
        int r = G >> 4, pos = G & 15;
        int g = (pos & 8) | ((pos ^ r) & 7);
        int gp = p0 + r; if (gp >= N) gp = N - 1;
        const float* src = F + (size_t)gp * DIM + g * 8;
        float4 x0 = ((const float4*)src)[0];
        float4 x1 = ((const float4*)src)[1];
        us8 o;
        o[0] = f2bf(x0.x); o[1] = f2bf(x0.y); o[2] = f2bf(x0.z); o[3] = f2bf(x0.w);
        o[4] = f2bf(x1.x); o[5] = f2bf(x1.y); o[6] = f2bf(x1.z); o[7] = f2bf(x1.w);
        *((us8*)&Fs[(size_t)G * 8]) = o;
    }

    // ---- precompute offsets ----
    int prA[4], xA[4], cnB[4], xB[4];
#pragma unroll
    for (int i = 0; i < 4; ++i) {
        int pr = wy * 64 + i * 16 + l15;
        prA[i] = pr * 128; xA[i] = quad ^ (pr & 7);
    }
#pragma unroll
    for (int j = 0; j < 4; ++j) {
        int cn = wx * 64 + j * 16 + l15;
        cnB[j] = cn * 128; xB[j] = quad ^ (cn & 7);
    }
    int csrc[8];
#pragma unroll
    for (int t = 0; t < 8; ++t) {
        int G = t * 256 + wave * 64 + lane;
        int r = G >> 4, pos = G & 15;
        int g = (pos & 8) | ((pos ^ r) & 7);
        csrc[t] = r * 256 + g * 8;      // elem offset within chunk (hi half)
    }
    float c2all[4][4];
#pragma unroll
    for (int cc = 0; cc < 4; ++cc)
#pragma unroll
        for (int j = 0; j < 4; ++j)
            c2all[cc][j] = c2g[cc * CC + wx * 64 + j * 16 + l15];

    float best1[16], best2[16];
    int bidx[16];
#pragma unroll
    for (int i = 0; i < 16; ++i) { best1[i] = 3.4e38f; best2[i] = 3.4e38f; bidx[i] = 0; }

#pragma unroll 1
    for (int cc = 0; cc < 4; ++cc) {
        f32x4 acc[4][4];
#pragma unroll
        for (int i = 0; i < 4; ++i)
#pragma unroll
            for (int j = 0; j < 4; ++j) acc[i][j] = f32x4{0.f, 0.f, 0.f, 0.f};

        __syncthreads();   // Cs free (also covers Fs writes on cc=0)
#pragma unroll
        for (int t = 0; t < 8; ++t)
            gload_lds16(Cp + (size_t)cc * CC * 256 + csrc[t],
                        &Cs[(size_t)(t * 256 + wave * 64) * 8]);
        __syncthreads();   // staging complete

#pragma unroll
        for (int s = 0; s < 4; ++s) {
            const int hs = (s & 2) << 2;
            const int ls = (s & 1) << 2;
            short8 a[4], b[4];
#pragma unroll
            for (int j = 0; j < 4; ++j)
                b[j] = *((const short8*)&Cs[cnB[j] + (hs | (xB[j] ^ ls)) * 8]);
#pragma unroll
            for (int i = 0; i < 4; ++i)
                a[i] = *((const short8*)&Fs[prA[i] + (hs | (xA[i] ^ ls)) * 8]);
#pragma unroll
            for (int i = 0; i < 4; ++i)
#pragma unroll
                for (int j = 0; j < 4; ++j)
                    acc[i][j] = __builtin_amdgcn_mfma_f32_16x16x32_bf16(
                        a[i], b[j], acc[i][j], 0, 0, 0);
        }

        // ---- epilogue fold ----
#pragma unroll
        for (int i = 0; i < 4; ++i)
#pragma unroll
            for (int reg = 0; reg < 4; ++reg) {
                int lr = i * 4 + reg;
#pragma unroll
                for (int j = 0; j < 4; ++j) {
                    float d = c2all[cc][j] - 2.0f * acc[i][j][reg];
                    int k = cc * CC + wx * 64 + j * 16 + l15;
                    if (d < best1[lr]) { best2[lr] = best1[lr]; best1[lr] = d; bidx[lr] = k; }
                    else if (d < best2[lr]) best2[lr] = d;
                }
            }
    }

    // ---- reduce across the 16 l15 lanes ----
    __syncthreads();
    float* sb1 = (float*)Cs;                 // [2][128]
    float* sb2 = sb1 + 256;
    int*   sk  = (int*)(sb2 + 256);

#pragma unroll
    for (int lr = 0; lr < 16; ++lr) {
        float b1 = best1[lr], b2 = best2[lr];
        int k1 = bidx[lr];
#pragma unroll
        for (int m = 1; m <= 8; m <<= 1) {
            float ob1 = __shfl_xor(b1, m);
            float ob2 = __shfl_xor(b2, m);
            int   ok1 = __shfl_xor(k1, m);
            float nb2 = fminf(fmaxf(b1, ob1), fminf(b2, ob2));
            if (ob1 < b1 || (ob1 == b1 && ok1 < k1)) { b1 = ob1; k1 = ok1; }
            b2 = nb2;
        }
        best1[lr] = b1; best2[lr] = b2; bidx[lr] = k1;
    }
    if (l15 == 0) {
#pragma unroll
        for (int lr = 0; lr < 16; ++lr) {
            int pl = wy * 64 + (lr >> 2) * 16 + quad * 4 + (lr & 3);
            sb1[wx * 128 + pl] = best1[lr];
            sb2[wx * 128 + pl] = best2[lr];
            sk [wx * 128 + pl] = bidx[lr];
        }
    }
    __syncthreads();

    if (tid < BM) {
        int p = p0 + tid;
        if (p < N) {
            float a1 = sb1[tid],       a2 = sb2[tid];        int akk = sk[tid];
            float c1 = sb1[128 + tid], cs2 = sb2[128 + tid]; int ckk = sk[128 + tid];
            float m2 = fminf(fmaxf(a1, c1), fminf(a2, cs2));
            float m1; int mk;
            if (c1 < a1 || (c1 == a1 && ckk < akk)) { m1 = c1; mk = ckk; }
            else                                    { m1 = a1; mk = akk; }
            assign_out[p] = (float)mk;
            if (m2 - m1 < TAU1) {
                int idx = atomicAdd(cntA, 1);
                if (idx < LISTA_CAP) listA[idx] = p;
                else {   // overflow valve: fp64-exact tier handles it
                    int ib = atomicAdd(cntB, 1);
                    if (ib < LISTB_CAP) listB[ib] = p;
                }
            }
        }
    }
}

// ---------------- TIER 2: hi/lo-split MFMA re-rank of listA points ----------------
// R4 kernel + gather via listA. 4-stage schedule, virtual K=384.
__global__ __launch_bounds__(256, 2)
void assign_lohi(const float* __restrict__ F, const ushort* __restrict__ Cp,
                 const float* __restrict__ c2g, float* __restrict__ assign_out,
                 const int* __restrict__ cntA, const int* __restrict__ listA,
                 int* __restrict__ cntB, int* __restrict__ listB, int N) {
    int cnt = *cntA; if (cnt > LISTA_CAP) cnt = LISTA_CAP;
    const int p0 = blockIdx.x * BM;
    if (p0 >= cnt) return;

    __shared__ __align__(16) ushort Fs[BM * 256];   // 65536 B
    __shared__ __align__(16) ushort Cs[CC * 64];    // 16384 B

    const int tid  = threadIdx.x;
    const int lane = tid & 63;
    const int wave = tid >> 6;
    const int quad = lane >> 4;
    const int l15  = lane & 15;
    const int wy   = wave >> 1;
    const int wx   = wave & 1;

    // ---- stage Fs (gathered): fp32 -> bf16 hi/lo, swizzled ----
    for (int G = tid; G < BM * 32; G += 256) {
        int r = G >> 5, pos = G & 31;
        int g = (pos & 24) | ((pos ^ r) & 7);
        int idx = p0 + r; if (idx >= cnt) idx = cnt - 1;
        int gp = listA[idx];
        const float* src = F + (size_t)gp * DIM + (g & 15) * 8;
        float4 x0 = ((const float4*)src)[0];
        float4 x1 = ((const float4*)src)[1];
        float xs[8] = {x0.x, x0.y, x0.z, x0.w, x1.x, x1.y, x1.z, x1.w};
        us8 o;
        if (g < 16) {
#pragma unroll
            for (int t = 0; t < 8; ++t) o[t] = f2bf(xs[t]);
        } else {
#pragma unroll
            for (int t = 0; t < 8; ++t) {
                ushort h = f2bf(xs[t]);
                o[t] = f2bf(xs[t] - bf2f(h));
            }
        }
        *((us8*)&Fs[(size_t)G * 8]) = o;
    }

    int aoff[4][2], boff[4][2];
#pragma unroll
    for (int i = 0; i < 4; ++i) {
        int pr = wy * 64 + i * 16 + l15;
#pragma unroll
        for (int s = 0; s < 2; ++s)
            aoff[i][s] = pr * 256 + (((s * 4 + quad) ^ (pr & 7)) * 8);
    }
#pragma unroll
    for (int j = 0; j < 4; ++j) {
        int cn = wx * 64 + j * 16 + l15;
#pragma unroll
        for (int s = 0; s < 2; ++s)
            boff[j][s] = cn * 64 + (((s * 4 + quad) ^ (cn & 7)) * 8);
    }
    int cpoff[4];
    ushort* ldsdst[4];
#pragma unroll
    for (int t = 0; t < 4; ++t) {
        int Gbase = t * 256 + wave * 64;
        int G = Gbase + lane;
        int r = G >> 3, pos = G & 7;
        int g = pos ^ (r & 7);
        cpoff[t] = r * 256 + g * 8;
        ldsdst[t] = &Cs[(size_t)Gbase * 8];
    }

    float best1[16], best2[16];
    int bidx[16];
#pragma unroll
    for (int i = 0; i < 16; ++i) { best1[i] = 3.4e38f; best2[i] = 3.4e38f; bidx[i] = 0; }

    for (int cc = 0; cc < K_CL / CC; ++cc) {
        const int ccbase = cc * (CC * 256);
        f32x4 acc[4][4];
#pragma unroll
        for (int i = 0; i < 4; ++i)
#pragma unroll
            for (int j = 0; j < 4; ++j) acc[i][j] = f32x4{0.f, 0.f, 0.f, 0.f};

#pragma unroll
        for (int st = 0; st < 4; ++st) {
            const int ak0 = st & 1;
            const int ak1 = (st < 2) ? (st + 2) : -1;

            __syncthreads();
#pragma unroll
            for (int t = 0; t < 4; ++t)
                gload_lds16(Cp + ccbase + st * 64 + cpoff[t], ldsdst[t]);
            __syncthreads();

#pragma unroll
            for (int s = 0; s < 2; ++s) {
                short8 b[4], a[4];
#pragma unroll
                for (int j = 0; j < 4; ++j)
                    b[j] = *((const short8*)&Cs[boff[j][s]]);
#pragma unroll
                for (int i = 0; i < 4; ++i)
                    a[i] = *((const short8*)&Fs[aoff[i][s] + ak0 * 64]);
#pragma unroll
                for (int i = 0; i < 4; ++i)
#pragma unroll
                    for (int j = 0; j < 4; ++j)
                        acc[i][j] = __builtin_amdgcn_mfma_f32_16x16x32_bf16(
                            a[i], b[j], acc[i][j], 0, 0, 0);
                if (ak1 >= 0) {
#pragma unroll
                    for (int i = 0; i < 4; ++i)
                        a[i] = *((const short8*)&Fs[aoff[i][s] + ak1 * 64]);
#pragma unroll
                    for (int i = 0; i < 4; ++i)
#pragma unroll
                        for (int j = 0; j < 4; ++j)
                            acc[i][j] = __builtin_amdgcn_mfma_f32_16x16x32_bf16(
                                a[i], b[j], acc[i][j], 0, 0, 0);
                }
            }
        }

        float c2v[4];
#pragma unroll
        for (int j = 0; j < 4; ++j)
            c2v[j] = c2g[cc * CC + wx * 64 + j * 16 + l15];
#pragma unroll
        for (int i = 0; i < 4; ++i)
#pragma unroll
            for (int reg = 0; reg < 4; ++reg) {
                int lr = i * 4 + reg;
#pragma unroll
                for (int j = 0; j < 4; ++j) {
                    float d = c2v[j] - 2.0f * acc[i][j][reg];
                    int k = cc * CC + wx * 64 + j * 16 + l15;
                    if (d < best1[lr]) { best2[lr] = best1[lr]; best1[lr] = d; bidx[lr] = k; }
                    else if (d < best2[lr]) best2[lr] = d;
                }
            }
    }

    __syncthreads();
    float* sb1 = (float*)Cs;
    float* sb2 = sb1 + 256;
    int*   sk  = (int*)(sb2 + 256);

#pragma unroll
    for (int lr = 0; lr < 16; ++lr) {
        float b1 = best1[lr], b2 = best2[lr];
        int k1 = bidx[lr];
#pragma unroll
        for (int m = 1; m <= 8; m <<= 1) {
            float ob1 = __shfl_xor(b1, m);
            float ob2 = __shfl_xor(b2, m);
            int   ok1 = __shfl_xor(k1, m);
            float nb2 = fminf(fmaxf(b1, ob1), fminf(b2, ob2));
            if (ob1 < b1 || (ob1 == b1 && ok1 < k1)) { b1 = ob1; k1 = ok1; }
            b2 = nb2;
        }
        best1[lr] = b1; best2[lr] = b2; bidx[lr] = k1;
    }
    if (l15 == 0) {
#pragma unroll
        for (int lr = 0; lr < 16; ++lr) {
            int pl = wy * 64 + (lr >> 2) * 16 + quad * 4 + (lr & 3);
            sb1[wx * 128 + pl] = best1[lr];
            sb2[wx * 128 + pl] = best2[lr];
            sk [wx * 128 + pl] = bidx[lr];
        }
    }
    __syncthreads();

    if (tid < BM && p0 + tid < cnt) {
        int p = listA[p0 + tid];
        float a1 = sb1[tid],       a2 = sb2[tid];        int akk = sk[tid];
        float c1 = sb1[128 + tid], cs2 = sb2[128 + tid]; int ckk = sk[128 + tid];
        float m2 = fminf(fmaxf(a1, c1), fminf(a2, cs2));
        float m1; int mk;
        if (c1 < a1 || (c1 == a1 && ckk < akk)) { m1 = c1; mk = ckk; }
        else                                    { m1 = a1; mk = akk; }
        assign_out[p] = (float)mk;
        if (m2 - m1 < TAU2) {
            int ib = atomicAdd(cntB, 1);
            if (ib < LISTB_CAP) listB[ib] = p;
        }
    }
}

// ---------------- TIER 3: fp64 re-argmin for near-tie points ----------------
__global__ void rescue_kernel(const float* __restrict__ F, const float* __restrict__ C,
                              const double* __restrict__ c2d,
                              const int* __restrict__ cntB,
                              const int* __restrict__ listB,
                              float* __restrict__ assign_out) {
    __shared__ double Frow[DIM];
    __shared__ double bd[256];
    __shared__ int    bk[256];
    int cnt = *cntB;
    if (cnt > LISTB_CAP) cnt = LISTB_CAP;
    for (int r = blockIdx.x; r < cnt; r += gridDim.x) {
        int p = listB[r];
        if (threadIdx.x < DIM) Frow[threadIdx.x] = (double)F[(size_t)p * DIM + threadIdx.x];
        __syncthreads();
        double b1 = 1e300; int k1 = 0x7fffffff;
        for (int k = threadIdx.x; k < K_CL; k += 256) {
            const float* c = C + (size_t)k * DIM;
            double acc = 0.0;
            for (int d = 0; d < DIM; ++d) acc += Frow[d] * (double)c[d];
            double dd = c2d[k] - 2.0 * acc;
            if (dd < b1 || (dd == b1 && k < k1)) { b1 = dd; k1 = k; }
        }
        bd[threadIdx.x] = b1; bk[threadIdx.x] = k1;
        __syncthreads();
        for (int s = 128; s > 0; s >>= 1) {
            if (threadIdx.x < s) {
                double ob = bd[threadIdx.x + s]; int ok = bk[threadIdx.x + s];
                if (ob < bd[threadIdx.x] || (ob == bd[threadIdx.x] && ok < bk[threadIdx.x])) {
                    bd[threadIdx.x] = ob; bk[threadIdx.x] = ok;
                }
            }
            __syncthreads();
        }
        if (threadIdx.x == 0) assign_out[p] = (float)bk[0];
        __syncthreads();
    }
}

// ---------------- kernel D: segment sum via K-range partition + queue ----------------
__global__ __launch_bounds__(256, 2)
void segsum2_kernel(const float* __restrict__ F, const float* __restrict__ assign_f,
                    float* __restrict__ sums, float* __restrict__ counts, int N) {
    __shared__ float acc[128 * 128];   // 64 KB  [localK][dim]
    __shared__ float cnt[128];
    __shared__ int   queue[QCAP];      // packed p*128 + localK
    __shared__ int   qn;

    const int tid    = threadIdx.x;
    const int krange = blockIdx.x & 3;
    const int part   = blockIdx.x >> 2;
    const int k0     = krange * 128;

    for (int i = tid; i < 128 * 128; i += 256) acc[i] = 0.f;
    if (tid < 128) cnt[tid] = 0.f;
    if (tid == 0) qn = 0;
    __syncthreads();

    const int per = (N + SS_PARTS - 1) / SS_PARTS;   // 1563
    int s0 = part * per;
    int s1 = s0 + per; if (s1 > N) s1 = N;

    for (int p = s0 + tid; p < s1; p += 256) {
        int a = (int)assign_f[p];
        int lc = a - k0;
        if ((unsigned)lc < 128u) {
            int idx = atomicAdd(&qn, 1);
            if (idx < QCAP) queue[idx] = p * 128 + lc;
            else {
                const float* row = F + (size_t)p * DIM;
                for (int d = 0; d < DIM; ++d)
                    unsafeAtomicAdd(&sums[(size_t)a * DIM + d], row[d]);
            }
            atomicAdd(&cnt[lc], 1.f);
        }
    }
    __syncthreads();

    int n = qn; if (n > QCAP) n = QCAP;
    int d   = tid & 127;
    int sub = tid >> 7;     // 0..1
    for (int q0 = sub; q0 < n; q0 += 8) {
        float v[4]; int lc[4];
#pragma unroll
        for (int t = 0; t < 4; ++t) {
            int q = q0 + 2 * t;
            if (q < n) {
                int pk = queue[q];
                lc[t] = pk & 127;
                v[t]  = F[(size_t)(pk >> 7) * DIM + d];
            } else lc[t] = -1;
        }
#pragma unroll
        for (int t = 0; t < 4; ++t)
            if (lc[t] >= 0) atomicAdd(&acc[lc[t] * 128 + d], v[t]);
    }
    __syncthreads();

    for (int i = tid; i < 128 * 128; i += 256) {
        float v = acc[i];
        if (v != 0.f)
            unsafeAtomicAdd(&sums[(size_t)(k0 + (i >> 7)) * DIM + (i & 127)], v);
    }
    if (tid < 128) {
        float v = cnt[tid];
        if (v != 0.f) unsafeAtomicAdd(&counts[k0 + tid], v);
    }
}

// ---------------- kernel E: new_centers = sums / max(counts,1) ----------------
__global__ void finalize_kernel(const float* __restrict__ sums,
                                const float* __restrict__ counts,
                                float* __restrict__ out) {
    int i = blockIdx.x * 256 + threadIdx.x;   // 0..65535
    int k = i >> 7;
    out[i] = sums[i] / fmaxf(counts[k], 1.0f);
}

extern "C" void kernel_launch(void* const* d_in, const int* in_sizes, int n_in,
                              void* d_out, int out_size, void* d_ws, size_t ws_size,
                              hipStream_t stream) {
    const float* F = (const float*)d_in[0];
    const float* C = (const float*)d_in[1];
    int N = in_sizes[0] / DIM;               // 200000

    float* out = (float*)d_out;
    float* centers_out = out;                // [512*128]
    float* assign_out  = out + K_CL * DIM;   // [N], as float

    // workspace layout (~870 KB)
    float*  sums   = (float*)d_ws;                  // 65536 f
    float*  counts = sums + K_CL * DIM;             // 512 f
    int*    cntA   = (int*)(counts + K_CL);         // [0]=A, [1]=B (8 ints pad)
    int*    cntB   = cntA + 1;
    int*    listA  = cntA + 8;                      // 65536 i
    int*    listB  = listA + LISTA_CAP;             // 16384 i
    float*  c2     = (float*)(listB + LISTB_CAP);   // 512 f
    double* c2d    = (double*)(c2 + K_CL);          // 512 d (8B-aligned)
    ushort* Cp     = (ushort*)(c2d + K_CL);         // 512*256 us

    // zero sums + counts + cntA/cntB
    hipMemsetAsync(d_ws, 0, (size_t)(K_CL * DIM + K_CL) * sizeof(float) + 32, stream);

    c2_kernel<<<2, 256, 0, stream>>>(C, c2, c2d);
    convC_kernel<<<K_CL * DIM / 256, 256, 0, stream>>>(C, Cp);

    int nb = (N + BM - 1) / BM;              // 1563
    assign_hi<<<nb, 256, 0, stream>>>(F, Cp, c2, assign_out, cntA, listA, cntB, listB, N);

    assign_lohi<<<LISTA_CAP / BM, 256, 0, stream>>>(F, Cp, c2, assign_out,
                                                    cntA, listA, cntB, listB, N);

    rescue_kernel<<<256, 256, 0, stream>>>(F, C, c2d, cntB, listB, assign_out);

    segsum2_kernel<<<4 * SS_PARTS, 256, 0, stream>>>(F, assign_out, sums, counts, N);

    finalize_kernel<<<K_CL * DIM / 256, 256, 0, stream>>>(sums, counts, centers_out);
}